// Round 1
// baseline (854.219 us; speedup 1.0000x reference)
//
#include <hip/hip_runtime.h>
#include <hip/hip_bf16.h>

#define NN 50000
#define NE 800000
#define H 64
#define AD 9
#define S 65   // LDS row stride (conflict-free)

__device__ __forceinline__ float swish_f(float v) {
    return v / (1.0f + __expf(-v));
}

// ---------------- edge/message kernel: 1 block = 64 edges ----------------
__global__ __launch_bounds__(256, 4) void edge_kernel(
    const float* __restrict__ x,
    const float* __restrict__ edge_attr,
    const float* __restrict__ amf,
    const float* __restrict__ Wm1, const float* __restrict__ Vm1, const float* __restrict__ bm1,
    const float* __restrict__ Wm2, const float* __restrict__ Vm2, const float* __restrict__ bm2,
    const int* __restrict__ ei,     // [2][NE]: row0 = src, row1 = dst
    float* __restrict__ agg)        // [NN][H]
{
    __shared__ float Abuf[129 * S];   // rows 0..63: x_i(=x[dst]), 64..127: x_j(=x[src]), 128: amf
    const int tid  = threadIdx.x;
    const int lane = tid & 63;
    const int wv   = tid >> 6;        // 0..3
    const int e0   = blockIdx.x * 64;

    // ---- stage (transposed into LDS) ----
    for (int t = 0; t < 16; ++t) {
        const int e  = wv + 4 * t;
        const int ge = e0 + e;
        const int dst = ei[NE + ge];   // wave-uniform -> scalar load
        const int src = ei[ge];
        Abuf[lane * S + e]        = x[dst * H + lane];
        Abuf[(64 + lane) * S + e] = x[src * H + lane];
    }
    if (wv == 0) {
        Abuf[128 * S + lane] = amf[e0 + lane];
    }
    __syncthreads();

    const int hb = __builtin_amdgcn_readfirstlane((tid >> 6) << 4);  // wave*16, uniform

    // per-edge attribute (kept in regs, reused for both gates)
    float ea[AD];
    {
        const int ge = e0 + lane;
        #pragma unroll
        for (int a = 0; a < AD; ++a) ea[a] = edge_attr[ge * AD + a];
    }

    // ---- GEMM1: [64e x 129] @ [129 x 16h] ----
    float acc[16];
    #pragma unroll
    for (int i = 0; i < 16; ++i) acc[i] = 0.0f;
    #pragma unroll 4
    for (int k = 0; k < 129; ++k) {
        const float xv = Abuf[k * S + lane];
        const float* Wk = Wm1 + k * H + hb;    // uniform -> s_load
        #pragma unroll
        for (int i = 0; i < 16; ++i) acc[i] = fmaf(xv, Wk[i], acc[i]);
    }

    float m1[16];
    #pragma unroll
    for (int i = 0; i < 16; ++i) {
        float g = 0.0f;
        #pragma unroll
        for (int a = 0; a < AD; ++a) g = fmaf(ea[a], Vm1[a * H + hb + i], g);
        m1[i] = swish_f(acc[i] * g + bm1[hb + i]);
    }
    __syncthreads();                    // all GEMM1 reads done
    // write m1 transposed into rows 0..63
    #pragma unroll
    for (int i = 0; i < 16; ++i) Abuf[(hb + i) * S + lane] = m1[i];
    __syncthreads();

    // ---- GEMM2: [64e x 64] @ [64 x 16h] ----
    #pragma unroll
    for (int i = 0; i < 16; ++i) acc[i] = 0.0f;
    #pragma unroll 4
    for (int k = 0; k < 64; ++k) {
        const float xv = Abuf[k * S + lane];
        const float* Wk = Wm2 + k * H + hb;
        #pragma unroll
        for (int i = 0; i < 16; ++i) acc[i] = fmaf(xv, Wk[i], acc[i]);
    }
    #pragma unroll
    for (int i = 0; i < 16; ++i) {
        float g = 0.0f;
        #pragma unroll
        for (int a = 0; a < AD; ++a) g = fmaf(ea[a], Vm2[a * H + hb + i], g);
        const float v = swish_f(acc[i] * g + bm2[hb + i]);
        Abuf[64 * S + lane * S + hb + i] = v;   // m2 row-major [e][h] in rows 64..127
    }
    __syncthreads();

    // ---- scatter: wave w takes 16 edges; lanes = 64 channels (coalesced atomics) ----
    for (int t = 0; t < 16; ++t) {
        const int e  = wv * 16 + t;
        const int dst = ei[NE + e0 + e];       // uniform
        const float v = Abuf[64 * S + e * S + lane];
        atomicAdd(&agg[dst * H + lane], v);
    }
}

// ---------------- node/update kernel: 1 block = 64 nodes ----------------
__global__ __launch_bounds__(256, 4) void node_kernel(
    const float* __restrict__ x,
    const float* __restrict__ agg,
    const float* __restrict__ node_attr,
    const float* __restrict__ Wu1, const float* __restrict__ Vu1, const float* __restrict__ bu1,
    const float* __restrict__ Wu2, const float* __restrict__ Vu2, const float* __restrict__ bu2,
    float* __restrict__ xout)
{
    __shared__ float Abuf[128 * S];   // rows 0..63: x, rows 64..127: agg (then u1T, then out)
    const int tid  = threadIdx.x;
    const int lane = tid & 63;
    const int wv   = tid >> 6;
    const int n0   = blockIdx.x * 64;

    for (int t = 0; t < 16; ++t) {
        const int n  = wv + 4 * t;
        const int gn = n0 + n;
        float xv = 0.0f, av = 0.0f;
        if (gn < NN) { xv = x[gn * H + lane]; av = agg[gn * H + lane]; }
        Abuf[lane * S + n]        = xv;
        Abuf[(64 + lane) * S + n] = av;
    }
    __syncthreads();

    const int hb = __builtin_amdgcn_readfirstlane((tid >> 6) << 4);

    const int gn  = n0 + lane;
    const int gnc = (gn < NN) ? gn : (NN - 1);
    float na[AD];
    #pragma unroll
    for (int a = 0; a < AD; ++a) na[a] = node_attr[gnc * AD + a];

    // ---- GEMM1: [64n x 128] @ [128 x 16h] ----
    float acc[16];
    #pragma unroll
    for (int i = 0; i < 16; ++i) acc[i] = 0.0f;
    #pragma unroll 4
    for (int k = 0; k < 128; ++k) {
        const float xv = Abuf[k * S + lane];
        const float* Wk = Wu1 + k * H + hb;
        #pragma unroll
        for (int i = 0; i < 16; ++i) acc[i] = fmaf(xv, Wk[i], acc[i]);
    }
    float u1[16];
    #pragma unroll
    for (int i = 0; i < 16; ++i) {
        float g = 0.0f;
        #pragma unroll
        for (int a = 0; a < AD; ++a) g = fmaf(na[a], Vu1[a * H + hb + i], g);
        u1[i] = swish_f(acc[i] * g + bu1[hb + i]);
    }
    __syncthreads();                 // all GEMM1 reads done
    // u1 transposed into rows 64..127 (x rows 0..63 preserved for residual)
    #pragma unroll
    for (int i = 0; i < 16; ++i) Abuf[(64 + hb + i) * S + lane] = u1[i];
    __syncthreads();

    // ---- GEMM2: [64n x 64] @ [64 x 16h] ----
    #pragma unroll
    for (int i = 0; i < 16; ++i) acc[i] = 0.0f;
    #pragma unroll 4
    for (int k = 0; k < 64; ++k) {
        const float xv = Abuf[(64 + k) * S + lane];
        const float* Wk = Wu2 + k * H + hb;
        #pragma unroll
        for (int i = 0; i < 16; ++i) acc[i] = fmaf(xv, Wk[i], acc[i]);
    }
    float xn[16];
    #pragma unroll
    for (int i = 0; i < 16; ++i) {
        float g = 0.0f;
        #pragma unroll
        for (int a = 0; a < AD; ++a) g = fmaf(na[a], Vu2[a * H + hb + i], g);
        const float u2 = acc[i] * g + bu2[hb + i];
        const float xr = Abuf[(hb + i) * S + lane];   // original x
        xn[i] = 0.7f * xr + 0.3f * u2;
    }
    __syncthreads();                 // all GEMM2 reads done
    #pragma unroll
    for (int i = 0; i < 16; ++i) Abuf[64 * S + lane * S + hb + i] = xn[i];  // [n][h]
    __syncthreads();

    for (int t = 0; t < 16; ++t) {
        const int n  = wv * 16 + t;
        const int gn2 = n0 + n;
        if (gn2 < NN) xout[gn2 * H + lane] = Abuf[64 * S + n * S + lane];
    }
}

extern "C" void kernel_launch(void* const* d_in, const int* in_sizes, int n_in,
                              void* d_out, int out_size, void* d_ws, size_t ws_size,
                              hipStream_t stream) {
    const float* x         = (const float*)d_in[0];
    const float* edge_attr = (const float*)d_in[1];
    const float* node_attr = (const float*)d_in[2];
    const float* amf       = (const float*)d_in[3];
    const float* Wm1 = (const float*)d_in[4];
    const float* Vm1 = (const float*)d_in[5];
    const float* bm1 = (const float*)d_in[6];
    const float* Wm2 = (const float*)d_in[7];
    const float* Vm2 = (const float*)d_in[8];
    const float* bm2 = (const float*)d_in[9];
    const float* Wu1 = (const float*)d_in[10];
    const float* Vu1 = (const float*)d_in[11];
    const float* bu1 = (const float*)d_in[12];
    const float* Wu2 = (const float*)d_in[13];
    const float* Vu2 = (const float*)d_in[14];
    const float* bu2 = (const float*)d_in[15];
    const int*   ei  = (const int*)d_in[16];

    float* out = (float*)d_out;
    float* agg = (float*)d_ws;                 // NN*H floats
    float* x1  = agg + (size_t)NN * H;         // NN*H floats

    const float* xin = x;
    for (int l = 0; l < 2; ++l) {
        float* xo = (l == 0) ? x1 : out;
        hipMemsetAsync(agg, 0, (size_t)NN * H * sizeof(float), stream);
        edge_kernel<<<NE / 64, 256, 0, stream>>>(
            xin, edge_attr, amf,
            Wm1 + (size_t)l * 129 * H, Vm1 + (size_t)l * AD * H, bm1 + (size_t)l * H,
            Wm2 + (size_t)l * H * H,   Vm2 + (size_t)l * AD * H, bm2 + (size_t)l * H,
            ei, agg);
        node_kernel<<<(NN + 63) / 64, 256, 0, stream>>>(
            xin, agg, node_attr,
            Wu1 + (size_t)l * 128 * H, Vu1 + (size_t)l * AD * H, bu1 + (size_t)l * H,
            Wu2 + (size_t)l * H * H,   Vu2 + (size_t)l * AD * H, bu2 + (size_t)l * H,
            xo);
        xin = xo;
    }
}

// Round 2
// 795.130 us; speedup vs baseline: 1.0743x; 1.0743x over previous
//
#include <hip/hip_runtime.h>
#include <hip/hip_bf16.h>

#define NN 50000
#define NE 800000
#define H  64
#define AD 9

typedef __attribute__((ext_vector_type(8)))  short short8;
typedef __attribute__((ext_vector_type(16))) float f32x16;
typedef unsigned int uint;
typedef unsigned short ushort;

union U8 { short8 v; uint u[4]; ushort s[8]; };

__device__ __forceinline__ f32x16 MFMA(short8 a, short8 b, f32x16 c) {
    return __builtin_amdgcn_mfma_f32_32x32x16_bf16(a, b, c, 0, 0, 0);
}

__device__ __forceinline__ ushort f2bf(float v) {
    __hip_bfloat16 b = __float2bfloat16(v);
    return *(ushort*)&b;
}
__device__ __forceinline__ uint pkbf(float a, float b) {
    uint r;
    asm volatile("v_cvt_pk_bf16_f32 %0, %1, %2" : "=v"(r) : "v"(a), "v"(b));
    return r;
}
__device__ __forceinline__ float bflo(uint u) { return __uint_as_float(u << 16); }
__device__ __forceinline__ float bfhi(uint u) { return __uint_as_float(u & 0xffff0000u); }

// cross-half exchange (semantics-safe alternative to v_permlane32_swap):
// given c0 (lo lanes: pair A0, hi lanes: pair B0) and c2 (lo: A1, hi: B1),
// produce d0 = {lo:A0, hi:A1(from lo lanes of c2)} and d2 = {lo:B0(from hi of c0), hi:B1}.
__device__ __forceinline__ void xhalf(uint& c0, uint& c2, int hi) {
    uint t = (uint)__shfl_xor((int)c2, 32);
    uint u = (uint)__shfl_xor((int)c0, 32);
    uint d0 = hi ? t : c0;
    uint d2 = hi ? c2 : u;
    c0 = d0; c2 = d2;
}

// ---------------- prep: x -> bf16 ----------------
__global__ void prep_x(const float* __restrict__ x, ushort* __restrict__ xb) {
    int t = blockIdx.x * 256 + threadIdx.x;
    if (t >= NN * H / 8) return;
    const float* p = x + (size_t)t * 8;
    U8 o;
    #pragma unroll
    for (int j = 0; j < 8; ++j) o.s[j] = f2bf(p[j]);
    *(short8*)(xb + (size_t)t * 8) = o.v;
}

// ---------------- prep: weights -> transposed, padded, bf16 ----------------
// edge blob (per layer, 17408 ushorts): W1T[64][168] | W2T[64][72] | V1T[64][16] | V2T[64][16]
// node blob (per layer, 15360 ushorts): WU1T[64][136] | WU2T[64][72] | VU1T[64][16] | VU2T[64][16]
__global__ void prep_w(const float* __restrict__ Wm1, const float* __restrict__ Vm1,
                       const float* __restrict__ Wm2, const float* __restrict__ Vm2,
                       const float* __restrict__ Wu1, const float* __restrict__ Vu1,
                       const float* __restrict__ Wu2, const float* __restrict__ Vu2,
                       ushort* __restrict__ wbE, ushort* __restrict__ wbN) {
    int t = blockIdx.x * 256 + threadIdx.x;
    float v = 0.f;
    if (t < 2 * 17408) {
        int l = t / 17408, o = t % 17408;
        if (o < 10752)      { int h = o / 168, k = o % 168;            if (k < 129) v = Wm1[l*8256 + k*64 + h]; }
        else if (o < 15360) { int o2 = o-10752; int h = o2/72, k = o2%72; if (k < 64)  v = Wm2[l*4096 + k*64 + h]; }
        else if (o < 16384) { int o2 = o-15360; int h = o2/16, a = o2%16; if (a < 9)   v = Vm1[l*576 + a*64 + h]; }
        else                { int o2 = o-16384; int h = o2/16, a = o2%16; if (a < 9)   v = Vm2[l*576 + a*64 + h]; }
        wbE[t] = f2bf(v);
    } else if (t < 2 * 17408 + 2 * 15360) {
        int u = t - 2 * 17408;
        int l = u / 15360, o = u % 15360;
        if (o < 8704)       { int h = o / 136, k = o % 136;            if (k < 128) v = Wu1[l*8192 + k*64 + h]; }
        else if (o < 13312) { int o2 = o-8704;  int h = o2/72, k = o2%72; if (k < 64)  v = Wu2[l*4096 + k*64 + h]; }
        else if (o < 14336) { int o2 = o-13312; int h = o2/16, a = o2%16; if (a < 9)   v = Vu1[l*576 + a*64 + h]; }
        else                { int o2 = o-14336; int h = o2/16, a = o2%16; if (a < 9)   v = Vu2[l*576 + a*64 + h]; }
        wbN[u] = f2bf(v);
    }
}

// ---------------- edge/message kernel: block = 256 edges, 4 waves x 64 edges ----------------
__global__ __launch_bounds__(256, 2) void edge_mfma(
    const ushort* __restrict__ xbf, const float* __restrict__ edge_attr,
    const float* __restrict__ amf, const ushort* __restrict__ wb,
    const float* __restrict__ b1, const float* __restrict__ b2,
    const int* __restrict__ ei, float* __restrict__ agg) {
    // LDS: W1T [64][168] (10752 ushorts) | M2 [256][72] (18432 ushorts)
    __shared__ __align__(16) ushort lds[10752 + 256 * 72];
    {
        const uint4* s4 = (const uint4*)wb;
        uint4* d4 = (uint4*)lds;
        for (int i = threadIdx.x; i < 1344; i += 256) d4[i] = s4[i];
    }
    __syncthreads();
    const ushort* W1T = lds;
    ushort* M2 = lds + 10752;

    const int lane = threadIdx.x & 63;
    const int wv   = threadIdx.x >> 6;
    const int hi   = lane >> 5;
    const int l31  = lane & 31;
    const int e0   = blockIdx.x * 256 + wv * 64;

    // pinned A-frags from global (L2-hot): W2T, V1T, V2T
    short8 aW2[4][2], aV1[2], aV2[2];
    #pragma unroll
    for (int m = 0; m < 2; ++m) {
        int r = l31 + 32 * m;
        aV1[m] = *(const short8*)(wb + 15360 + r * 16 + hi * 8);
        aV2[m] = *(const short8*)(wb + 16384 + r * 16 + hi * 8);
        #pragma unroll
        for (int s = 0; s < 4; ++s)
            aW2[s][m] = *(const short8*)(wb + 10752 + r * 72 + s * 16 + hi * 8);
    }

    for (int nr = 0; nr < 2; ++nr) {
        const int e   = e0 + nr * 32 + l31;
        const int dst = ei[NE + e];
        const int src = ei[e];

        float ea[AD];
        #pragma unroll
        for (int a = 0; a < AD; ++a) ea[a] = edge_attr[(size_t)e * AD + a];

        // gate B-frag (k = attr dim, padded to 16)
        U8 bea;
        {
            uint g0 = pkbf(ea[0], ea[1]), g1 = pkbf(ea[2], ea[3]);
            uint g2 = pkbf(ea[4], ea[5]), g3 = pkbf(ea[6], ea[7]);
            uint g8 = pkbf(ea[8], 0.f);
            bea.u[0] = hi ? g8 : g0;
            bea.u[1] = hi ? 0u : g1;
            bea.u[2] = hi ? 0u : g2;
            bea.u[3] = hi ? 0u : g3;
        }
        f32x16 gA0 = {}, gA1 = {};
        gA0 = MFMA(aV1[0], bea.v, gA0);
        gA1 = MFMA(aV1[1], bea.v, gA1);

        // GEMM1: m1T[h][e] = sum_k W1[k][h] * feat[e][k], feat = [x_i | x_j | amf]
        f32x16 mA0 = {}, mA1 = {};
        const ushort* xd = xbf + (size_t)dst * H;
        const ushort* xs = xbf + (size_t)src * H;
        #pragma unroll
        for (int s = 0; s < 8; ++s) {
            short8 bx = *(const short8*)((s < 4 ? xd : xs) + (s & 3) * 16 + hi * 8);
            short8 a0 = *(const short8*)(W1T + l31 * 168 + s * 16 + hi * 8);
            short8 a1 = *(const short8*)(W1T + (l31 + 32) * 168 + s * 16 + hi * 8);
            mA0 = MFMA(a0, bx, mA0);
            mA1 = MFMA(a1, bx, mA1);
        }
        {   // amf step: k = 128..143
            float av = amf[e];
            U8 bx;
            bx.u[0] = hi ? 0u : pkbf(av, 0.f);
            bx.u[1] = 0; bx.u[2] = 0; bx.u[3] = 0;
            short8 a0 = *(const short8*)(W1T + l31 * 168 + 128 + hi * 8);
            short8 a1 = *(const short8*)(W1T + (l31 + 32) * 168 + 128 + hi * 8);
            mA0 = MFMA(a0, bx.v, mA0);
            mA1 = MFMA(a1, bx.v, mA1);
        }

        // swish(m*gate + b1), pack into GEMM2 B-frags (k = h of m1)
        short8 bm[4];
        #pragma unroll
        for (int m = 0; m < 2; ++m) {
            const f32x16 mc = m ? mA1 : mA0;
            const f32x16 gc = m ? gA1 : gA0;
            float y[16];
            #pragma unroll
            for (int r = 0; r < 16; ++r) {
                int h0 = (r & 3) + 8 * (r >> 2) + 32 * m;
                float bb = hi ? b1[h0 + 4] : b1[h0];
                float v = fmaf(mc[r], gc[r], bb);
                y[r] = v / (1.f + __expf(-v));
            }
            #pragma unroll
            for (int g = 0; g < 2; ++g) {
                uint c0 = pkbf(y[g*8+0], y[g*8+1]);
                uint c1 = pkbf(y[g*8+2], y[g*8+3]);
                uint c2 = pkbf(y[g*8+4], y[g*8+5]);
                uint c3 = pkbf(y[g*8+6], y[g*8+7]);
                xhalf(c0, c2, hi);
                xhalf(c1, c3, hi);
                U8 q; q.u[0] = c0; q.u[1] = c1; q.u[2] = c2; q.u[3] = c3;
                bm[2*m + g] = q.v;
            }
        }

        // GEMM2 + gate2
        f32x16 h0a = {}, h1a = {};
        h0a = MFMA(aV2[0], bea.v, h0a);
        h1a = MFMA(aV2[1], bea.v, h1a);
        f32x16 p0 = {}, p1 = {};
        #pragma unroll
        for (int s = 0; s < 4; ++s) {
            p0 = MFMA(aW2[s][0], bm[s], p0);
            p1 = MFMA(aW2[s][1], bm[s], p1);
        }

        // swish(m2*gate2 + b2), pack, transpose through LDS
        #pragma unroll
        for (int m = 0; m < 2; ++m) {
            const f32x16 mc = m ? p1 : p0;
            const f32x16 gc = m ? h1a : h0a;
            float y[16];
            #pragma unroll
            for (int r = 0; r < 16; ++r) {
                int h0 = (r & 3) + 8 * (r >> 2) + 32 * m;
                float bb = hi ? b2[h0 + 4] : b2[h0];
                float v = fmaf(mc[r], gc[r], bb);
                y[r] = v / (1.f + __expf(-v));
            }
            #pragma unroll
            for (int g = 0; g < 2; ++g) {
                uint c0 = pkbf(y[g*8+0], y[g*8+1]);
                uint c1 = pkbf(y[g*8+2], y[g*8+3]);
                uint c2 = pkbf(y[g*8+4], y[g*8+5]);
                uint c3 = pkbf(y[g*8+6], y[g*8+7]);
                xhalf(c0, c2, hi);
                xhalf(c1, c3, hi);
                U8 q; q.u[0] = c0; q.u[1] = c1; q.u[2] = c2; q.u[3] = c3;
                *(short8*)(M2 + (wv * 64 + nr * 32 + l31) * 72 + (2*m + g) * 16 + hi * 8) = q.v;
            }
        }
    }

    // scatter: 2 edges per instruction, lanes = channel pairs (coalesced atomics)
    const uint* M2d = (const uint*)M2;
    const int bbase = blockIdx.x * 256;
    for (int t = 0; t < 32; ++t) {
        int ep = wv * 64 + 2 * t + hi;
        int dd = ei[NE + bbase + ep];
        uint pv = M2d[ep * 36 + l31];
        atomicAdd(&agg[(size_t)dd * H + 2 * l31],     bflo(pv));
        atomicAdd(&agg[(size_t)dd * H + 2 * l31 + 1], bfhi(pv));
    }
}

// ---------------- node/update kernel: block = 128 nodes, 4 waves x 32 nodes ----------------
__global__ __launch_bounds__(256, 2) void node_mfma(
    const ushort* __restrict__ xbf, const float* __restrict__ agg,
    const float* __restrict__ node_attr, const ushort* __restrict__ wb,
    const float* __restrict__ b1, const float* __restrict__ b2,
    ushort* __restrict__ xnext, float* __restrict__ outf, int last) {
    __shared__ __align__(16) ushort lds[8704];   // WU1T [64][136]
    {
        const uint4* s4 = (const uint4*)wb;
        uint4* d4 = (uint4*)lds;
        for (int i = threadIdx.x; i < 1088; i += 256) d4[i] = s4[i];
    }
    __syncthreads();
    const ushort* W1T = lds;

    const int lane = threadIdx.x & 63;
    const int wv   = threadIdx.x >> 6;
    const int hi   = lane >> 5;
    const int l31  = lane & 31;
    const int n    = blockIdx.x * 128 + wv * 32 + l31;
    const int nc   = n < NN ? n : NN - 1;

    short8 aW2[4][2], aV1[2], aV2[2];
    #pragma unroll
    for (int m = 0; m < 2; ++m) {
        int r = l31 + 32 * m;
        aV1[m] = *(const short8*)(wb + 13312 + r * 16 + hi * 8);
        aV2[m] = *(const short8*)(wb + 14336 + r * 16 + hi * 8);
        #pragma unroll
        for (int s = 0; s < 4; ++s)
            aW2[s][m] = *(const short8*)(wb + 8704 + r * 72 + s * 16 + hi * 8);
    }

    float na[AD];
    #pragma unroll
    for (int a = 0; a < AD; ++a) na[a] = node_attr[(size_t)nc * AD + a];

    U8 bna;
    {
        uint g0 = pkbf(na[0], na[1]), g1 = pkbf(na[2], na[3]);
        uint g2 = pkbf(na[4], na[5]), g3 = pkbf(na[6], na[7]);
        uint g8 = pkbf(na[8], 0.f);
        bna.u[0] = hi ? g8 : g0;
        bna.u[1] = hi ? 0u : g1;
        bna.u[2] = hi ? 0u : g2;
        bna.u[3] = hi ? 0u : g3;
    }
    f32x16 gA0 = {}, gA1 = {};
    gA0 = MFMA(aV1[0], bna.v, gA0);
    gA1 = MFMA(aV1[1], bna.v, gA1);

    // GEMM1: k 0..63 = x (bf16), k 64..127 = agg (f32 -> bf16)
    f32x16 mA0 = {}, mA1 = {};
    #pragma unroll
    for (int s = 0; s < 8; ++s) {
        short8 bx;
        if (s < 4) {
            bx = *(const short8*)(xbf + (size_t)nc * H + s * 16 + hi * 8);
        } else {
            const float* ap = agg + (size_t)nc * H + (s - 4) * 16 + hi * 8;
            float4 u0 = *(const float4*)ap;
            float4 u1 = *(const float4*)(ap + 4);
            U8 q;
            q.u[0] = pkbf(u0.x, u0.y); q.u[1] = pkbf(u0.z, u0.w);
            q.u[2] = pkbf(u1.x, u1.y); q.u[3] = pkbf(u1.z, u1.w);
            bx = q.v;
        }
        short8 a0 = *(const short8*)(W1T + l31 * 136 + s * 16 + hi * 8);
        short8 a1 = *(const short8*)(W1T + (l31 + 32) * 136 + s * 16 + hi * 8);
        mA0 = MFMA(a0, bx, mA0);
        mA1 = MFMA(a1, bx, mA1);
    }

    short8 bm[4];
    #pragma unroll
    for (int m = 0; m < 2; ++m) {
        const f32x16 mc = m ? mA1 : mA0;
        const f32x16 gc = m ? gA1 : gA0;
        float y[16];
        #pragma unroll
        for (int r = 0; r < 16; ++r) {
            int h0 = (r & 3) + 8 * (r >> 2) + 32 * m;
            float bb = hi ? b1[h0 + 4] : b1[h0];
            float v = fmaf(mc[r], gc[r], bb);
            y[r] = v / (1.f + __expf(-v));
        }
        #pragma unroll
        for (int g = 0; g < 2; ++g) {
            uint c0 = pkbf(y[g*8+0], y[g*8+1]);
            uint c1 = pkbf(y[g*8+2], y[g*8+3]);
            uint c2 = pkbf(y[g*8+4], y[g*8+5]);
            uint c3 = pkbf(y[g*8+6], y[g*8+7]);
            xhalf(c0, c2, hi);
            xhalf(c1, c3, hi);
            U8 q; q.u[0] = c0; q.u[1] = c1; q.u[2] = c2; q.u[3] = c3;
            bm[2*m + g] = q.v;
        }
    }

    f32x16 h0a = {}, h1a = {};
    h0a = MFMA(aV2[0], bna.v, h0a);
    h1a = MFMA(aV2[1], bna.v, h1a);
    f32x16 p0 = {}, p1 = {};
    #pragma unroll
    for (int s = 0; s < 4; ++s) {
        p0 = MFMA(aW2[s][0], bm[s], p0);
        p1 = MFMA(aW2[s][1], bm[s], p1);
    }

    // u2 = m*gate + b (no swish), residual blend, store
    #pragma unroll
    for (int m = 0; m < 2; ++m) {
        const f32x16 mc = m ? p1 : p0;
        const f32x16 gc = m ? h1a : h0a;
        float y[16];
        #pragma unroll
        for (int r = 0; r < 16; ++r) {
            int h0 = (r & 3) + 8 * (r >> 2) + 32 * m;
            float bb = hi ? b2[h0 + 4] : b2[h0];
            y[r] = fmaf(mc[r], gc[r], bb);
        }
        #pragma unroll
        for (int g = 0; g < 2; ++g) {
            uint c0 = pkbf(y[g*8+0], y[g*8+1]);
            uint c1 = pkbf(y[g*8+2], y[g*8+3]);
            uint c2 = pkbf(y[g*8+4], y[g*8+5]);
            uint c3 = pkbf(y[g*8+6], y[g*8+7]);
            xhalf(c0, c2, hi);
            xhalf(c1, c3, hi);
            int goff = (2*m + g) * 16 + hi * 8;
            U8 xb; xb.v = *(const short8*)(xbf + (size_t)nc * H + goff);
            float o[8];
            uint cc[4] = {c0, c1, c2, c3};
            #pragma unroll
            for (int j = 0; j < 4; ++j) {
                o[2*j]   = 0.7f * bflo((uint)xb.u[j]) + 0.3f * bflo(cc[j]);
                o[2*j+1] = 0.7f * bfhi((uint)xb.u[j]) + 0.3f * bfhi(cc[j]);
            }
            if (n < NN) {
                if (last) {
                    float4 w0 = {o[0], o[1], o[2], o[3]};
                    float4 w1 = {o[4], o[5], o[6], o[7]};
                    *(float4*)(outf + (size_t)n * H + goff)     = w0;
                    *(float4*)(outf + (size_t)n * H + goff + 4) = w1;
                } else {
                    U8 q;
                    #pragma unroll
                    for (int j = 0; j < 4; ++j) q.u[j] = pkbf(o[2*j], o[2*j+1]);
                    *(short8*)(xnext + (size_t)n * H + goff) = q.v;
                }
            }
        }
    }
}

extern "C" void kernel_launch(void* const* d_in, const int* in_sizes, int n_in,
                              void* d_out, int out_size, void* d_ws, size_t ws_size,
                              hipStream_t stream) {
    const float* x         = (const float*)d_in[0];
    const float* edge_attr = (const float*)d_in[1];
    const float* node_attr = (const float*)d_in[2];
    const float* amf       = (const float*)d_in[3];
    const float* Wm1 = (const float*)d_in[4];
    const float* Vm1 = (const float*)d_in[5];
    const float* bm1 = (const float*)d_in[6];
    const float* Wm2 = (const float*)d_in[7];
    const float* Vm2 = (const float*)d_in[8];
    const float* bm2 = (const float*)d_in[9];
    const float* Wu1 = (const float*)d_in[10];
    const float* Vu1 = (const float*)d_in[11];
    const float* bu1 = (const float*)d_in[12];
    const float* Wu2 = (const float*)d_in[13];
    const float* Vu2 = (const float*)d_in[14];
    const float* bu2 = (const float*)d_in[15];
    const int*   ei  = (const int*)d_in[16];

    float* out = (float*)d_out;
    float* agg = (float*)d_out;               // agg shares d_out (safe: per-block row ownership)

    ushort* xbf0 = (ushort*)d_ws;             // NN*H bf16
    ushort* xbf1 = xbf0 + (size_t)NN * H;
    ushort* wbE  = xbf1 + (size_t)NN * H;     // 2 * 17408 ushorts
    ushort* wbN  = wbE + 2 * 17408;           // 2 * 15360 ushorts

    prep_x<<<(NN * H / 8 + 255) / 256, 256, 0, stream>>>(x, xbf0);
    prep_w<<<256, 256, 0, stream>>>(Wm1, Vm1, Wm2, Vm2, Wu1, Vu1, Wu2, Vu2, wbE, wbN);

    for (int l = 0; l < 2; ++l) {
        const ushort* xb = (l == 0) ? xbf0 : xbf1;
        hipMemsetAsync(agg, 0, (size_t)NN * H * sizeof(float), stream);
        edge_mfma<<<NE / 256, 256, 0, stream>>>(
            xb, edge_attr, amf, wbE + (size_t)l * 17408,
            bm1 + l * H, bm2 + l * H, ei, agg);
        node_mfma<<<(NN + 127) / 128, 256, 0, stream>>>(
            xb, agg, node_attr, wbN + (size_t)l * 15360,
            bu1 + l * H, bu2 + l * H, xbf1, out, (l == 1) ? 1 : 0);
    }
}

// Round 3
// 383.424 us; speedup vs baseline: 2.2279x; 2.0738x over previous
//
#include <hip/hip_runtime.h>
#include <hip/hip_bf16.h>

#define NN 50000
#define NE 800000
#define H  64
#define AD 9

typedef __attribute__((ext_vector_type(8)))  short short8;
typedef __attribute__((ext_vector_type(16))) float f32x16;
typedef unsigned int uint;
typedef unsigned short ushort;

union U8 { short8 v; uint u[4]; ushort s[8]; };

__device__ __forceinline__ f32x16 MFMA(short8 a, short8 b, f32x16 c) {
    return __builtin_amdgcn_mfma_f32_32x32x16_bf16(a, b, c, 0, 0, 0);
}

__device__ __forceinline__ ushort f2bf(float v) {
    __hip_bfloat16 b = __float2bfloat16(v);
    return *(ushort*)&b;
}
__device__ __forceinline__ uint pkbf(float a, float b) {
    uint r;
    asm volatile("v_cvt_pk_bf16_f32 %0, %1, %2" : "=v"(r) : "v"(a), "v"(b));
    return r;
}
__device__ __forceinline__ float bflo(uint u) { return __uint_as_float(u << 16); }
__device__ __forceinline__ float bfhi(uint u) { return __uint_as_float(u & 0xffff0000u); }

__device__ __forceinline__ void xhalf(uint& c0, uint& c2, int hi) {
    uint t = (uint)__shfl_xor((int)c2, 32);
    uint u = (uint)__shfl_xor((int)c0, 32);
    uint d0 = hi ? t : c0;
    uint d2 = hi ? c2 : u;
    c0 = d0; c2 = d2;
}

// ---------------- prep: x -> bf16 ----------------
__global__ void prep_x(const float* __restrict__ x, ushort* __restrict__ xb) {
    int t = blockIdx.x * 256 + threadIdx.x;
    if (t >= NN * H / 8) return;
    const float* p = x + (size_t)t * 8;
    U8 o;
    #pragma unroll
    for (int j = 0; j < 8; ++j) o.s[j] = f2bf(p[j]);
    *(short8*)(xb + (size_t)t * 8) = o.v;
}

// ---------------- prep: weights -> transposed, padded, bf16 ----------------
__global__ void prep_w(const float* __restrict__ Wm1, const float* __restrict__ Vm1,
                       const float* __restrict__ Wm2, const float* __restrict__ Vm2,
                       const float* __restrict__ Wu1, const float* __restrict__ Vu1,
                       const float* __restrict__ Wu2, const float* __restrict__ Vu2,
                       ushort* __restrict__ wbE, ushort* __restrict__ wbN) {
    int t = blockIdx.x * 256 + threadIdx.x;
    float v = 0.f;
    if (t < 2 * 17408) {
        int l = t / 17408, o = t % 17408;
        if (o < 10752)      { int h = o / 168, k = o % 168;            if (k < 129) v = Wm1[l*8256 + k*64 + h]; }
        else if (o < 15360) { int o2 = o-10752; int h = o2/72, k = o2%72; if (k < 64)  v = Wm2[l*4096 + k*64 + h]; }
        else if (o < 16384) { int o2 = o-15360; int h = o2/16, a = o2%16; if (a < 9)   v = Vm1[l*576 + a*64 + h]; }
        else                { int o2 = o-16384; int h = o2/16, a = o2%16; if (a < 9)   v = Vm2[l*576 + a*64 + h]; }
        wbE[t] = f2bf(v);
    } else if (t < 2 * 17408 + 2 * 15360) {
        int u = t - 2 * 17408;
        int l = u / 15360, o = u % 15360;
        if (o < 8704)       { int h = o / 136, k = o % 136;            if (k < 128) v = Wu1[l*8192 + k*64 + h]; }
        else if (o < 13312) { int o2 = o-8704;  int h = o2/72, k = o2%72; if (k < 64)  v = Wu2[l*4096 + k*64 + h]; }
        else if (o < 14336) { int o2 = o-13312; int h = o2/16, a = o2%16; if (a < 9)   v = Vu1[l*576 + a*64 + h]; }
        else                { int o2 = o-14336; int h = o2/16, a = o2%16; if (a < 9)   v = Vu2[l*576 + a*64 + h]; }
        wbN[u] = f2bf(v);
    }
}

// ---------------- CSR build ----------------
__global__ void hist_k(const int* __restrict__ ei, int* __restrict__ cnt) {
    int t = blockIdx.x * 256 + threadIdx.x;
    if (t < NE) atomicAdd(&cnt[ei[NE + t]], 1);
}

__global__ void scan1_k(const int* __restrict__ cnt, int* __restrict__ partial,
                        int* __restrict__ btot) {
    __shared__ int sh[256];
    const int b = blockIdx.x, tid = threadIdx.x, i = b * 256 + tid;
    int c = cnt[i];
    sh[tid] = c; __syncthreads();
    int run = c;
    for (int off = 1; off < 256; off <<= 1) {
        int t = (tid >= off) ? sh[tid - off] : 0;
        __syncthreads();
        run += t; sh[tid] = run; __syncthreads();
    }
    partial[i] = run - c;
    if (tid == 255) btot[b] = run;
}

__global__ void scan2_k(const int* __restrict__ btot, int* __restrict__ boff) {
    __shared__ int sh[256];
    const int tid = threadIdx.x;
    int c = (tid < 200) ? btot[tid] : 0;
    sh[tid] = c; __syncthreads();
    int run = c;
    for (int off = 1; off < 256; off <<= 1) {
        int t = (tid >= off) ? sh[tid - off] : 0;
        __syncthreads();
        run += t; sh[tid] = run; __syncthreads();
    }
    boff[tid] = run - c;
}

__global__ void scan3_k(const int* __restrict__ partial, const int* __restrict__ boff,
                        int* __restrict__ cursor) {
    int b = blockIdx.x, i = b * 256 + threadIdx.x;
    if (i < NN) cursor[i] = partial[i] + boff[b];
}

__global__ void fill_k(const int* __restrict__ ei, const float* __restrict__ edge_attr,
                       const float* __restrict__ amf, int* __restrict__ cursor,
                       int* __restrict__ srcS, int* __restrict__ dstS,
                       float* __restrict__ amfS, float* __restrict__ eaS) {
    int e = blockIdx.x * 256 + threadIdx.x;
    if (e >= NE) return;
    const int dst = ei[NE + e], src = ei[e];
    const int pos = atomicAdd(&cursor[dst], 1);
    srcS[pos] = src; dstS[pos] = dst; amfS[pos] = amf[e];
    #pragma unroll
    for (int a = 0; a < AD; ++a) eaS[(size_t)pos * AD + a] = edge_attr[(size_t)e * AD + a];
}

// ---------------- edge/message kernel: block = 256 dst-sorted edges ----------------
__global__ __launch_bounds__(256, 4) void edge_mfma(
    const ushort* __restrict__ xbf, const float* __restrict__ eaS,
    const float* __restrict__ amfS, const int* __restrict__ srcS,
    const int* __restrict__ dstS, const ushort* __restrict__ wb,
    const float* __restrict__ b1, const float* __restrict__ b2,
    float* __restrict__ agg) {
    // LDS: W1T [64][168] (10752 ushorts) | per-wave M2 [32][68] bf16
    __shared__ __align__(16) ushort lds[10752 + 4 * 32 * 68];
    {
        const uint4* s4 = (const uint4*)wb;
        uint4* d4 = (uint4*)lds;
        for (int i = threadIdx.x; i < 1344; i += 256) d4[i] = s4[i];
    }
    __syncthreads();
    const ushort* W1T = lds;

    const int lane = threadIdx.x & 63;
    const int wv   = threadIdx.x >> 6;
    const int hi   = lane >> 5;
    const int l31  = lane & 31;
    ushort* M2 = lds + 10752 + wv * (32 * 68);

    // pinned A-frags from global (L2-hot): W2T, V1T, V2T
    short8 aW2[4][2], aV1[2], aV2[2];
    #pragma unroll
    for (int m = 0; m < 2; ++m) {
        int r = l31 + 32 * m;
        aV1[m] = *(const short8*)(wb + 15360 + r * 16 + hi * 8);
        aV2[m] = *(const short8*)(wb + 16384 + r * 16 + hi * 8);
        #pragma unroll
        for (int s = 0; s < 4; ++s)
            aW2[s][m] = *(const short8*)(wb + 10752 + r * 72 + s * 16 + hi * 8);
    }

    for (int nr = 0; nr < 2; ++nr) {
        const int i   = blockIdx.x * 256 + wv * 64 + nr * 32 + l31;
        const int dst = dstS[i];
        const int src = srcS[i];

        float ea[AD];
        #pragma unroll
        for (int a = 0; a < AD; ++a) ea[a] = eaS[(size_t)i * AD + a];

        U8 bea;
        {
            uint g0 = pkbf(ea[0], ea[1]), g1 = pkbf(ea[2], ea[3]);
            uint g2 = pkbf(ea[4], ea[5]), g3 = pkbf(ea[6], ea[7]);
            uint g8 = pkbf(ea[8], 0.f);
            bea.u[0] = hi ? g8 : g0;
            bea.u[1] = hi ? 0u : g1;
            bea.u[2] = hi ? 0u : g2;
            bea.u[3] = hi ? 0u : g3;
        }
        f32x16 gA0 = {}, gA1 = {};
        gA0 = MFMA(aV1[0], bea.v, gA0);
        gA1 = MFMA(aV1[1], bea.v, gA1);

        // GEMM1: m1T[h][e] = sum_k W1[k][h] * [x_i | x_j | amf][e][k]
        f32x16 mA0 = {}, mA1 = {};
        const ushort* xd = xbf + (size_t)dst * H;
        const ushort* xs = xbf + (size_t)src * H;
        #pragma unroll
        for (int s = 0; s < 8; ++s) {
            short8 bx = *(const short8*)((s < 4 ? xd : xs) + (s & 3) * 16 + hi * 8);
            short8 a0 = *(const short8*)(W1T + l31 * 168 + s * 16 + hi * 8);
            short8 a1 = *(const short8*)(W1T + (l31 + 32) * 168 + s * 16 + hi * 8);
            mA0 = MFMA(a0, bx, mA0);
            mA1 = MFMA(a1, bx, mA1);
        }
        {
            float av = amfS[i];
            U8 bx;
            bx.u[0] = hi ? 0u : pkbf(av, 0.f);
            bx.u[1] = 0; bx.u[2] = 0; bx.u[3] = 0;
            short8 a0 = *(const short8*)(W1T + l31 * 168 + 128 + hi * 8);
            short8 a1 = *(const short8*)(W1T + (l31 + 32) * 168 + 128 + hi * 8);
            mA0 = MFMA(a0, bx.v, mA0);
            mA1 = MFMA(a1, bx.v, mA1);
        }

        // swish(m*gate + b1) -> GEMM2 B-frags
        short8 bm[4];
        #pragma unroll
        for (int m = 0; m < 2; ++m) {
            const f32x16 mc = m ? mA1 : mA0;
            const f32x16 gc = m ? gA1 : gA0;
            float y[16];
            #pragma unroll
            for (int r = 0; r < 16; ++r) {
                int h0 = (r & 3) + 8 * (r >> 2) + 32 * m;
                float bb = hi ? b1[h0 + 4] : b1[h0];
                float v = fmaf(mc[r], gc[r], bb);
                y[r] = v / (1.f + __expf(-v));
            }
            #pragma unroll
            for (int g = 0; g < 2; ++g) {
                uint c0 = pkbf(y[g*8+0], y[g*8+1]);
                uint c1 = pkbf(y[g*8+2], y[g*8+3]);
                uint c2 = pkbf(y[g*8+4], y[g*8+5]);
                uint c3 = pkbf(y[g*8+6], y[g*8+7]);
                xhalf(c0, c2, hi);
                xhalf(c1, c3, hi);
                U8 q; q.u[0] = c0; q.u[1] = c1; q.u[2] = c2; q.u[3] = c3;
                bm[2*m + g] = q.v;
            }
        }

        // GEMM2 + gate2
        f32x16 h0a = {}, h1a = {};
        h0a = MFMA(aV2[0], bea.v, h0a);
        h1a = MFMA(aV2[1], bea.v, h1a);
        f32x16 p0 = {}, p1 = {};
        #pragma unroll
        for (int s = 0; s < 4; ++s) {
            p0 = MFMA(aW2[s][0], bm[s], p0);
            p1 = MFMA(aW2[s][1], bm[s], p1);
        }

        // swish(m2*gate2 + b2), pack, stage per-wave rows [32][68]
        #pragma unroll
        for (int m = 0; m < 2; ++m) {
            const f32x16 mc = m ? p1 : p0;
            const f32x16 gc = m ? h1a : h0a;
            float y[16];
            #pragma unroll
            for (int r = 0; r < 16; ++r) {
                int h0 = (r & 3) + 8 * (r >> 2) + 32 * m;
                float bb = hi ? b2[h0 + 4] : b2[h0];
                float v = fmaf(mc[r], gc[r], bb);
                y[r] = v / (1.f + __expf(-v));
            }
            #pragma unroll
            for (int g = 0; g < 2; ++g) {
                uint c0 = pkbf(y[g*8+0], y[g*8+1]);
                uint c1 = pkbf(y[g*8+2], y[g*8+3]);
                uint c2 = pkbf(y[g*8+4], y[g*8+5]);
                uint c3 = pkbf(y[g*8+6], y[g*8+7]);
                xhalf(c0, c2, hi);
                xhalf(c1, c3, hi);
                U8 q; q.u[0] = c0; q.u[1] = c1; q.u[2] = c2; q.u[3] = c3;
                *(short8*)(M2 + l31 * 68 + (2*m + g) * 16 + hi * 8) = q.v;
            }
        }

        asm volatile("s_waitcnt lgkmcnt(0)" ::: "memory");
        __builtin_amdgcn_sched_barrier(0);

        // segmented reduce over the wave's 32 dst-sorted rows; lane = channel
        float acc = 0.f;
        int cur = __builtin_amdgcn_readlane(dst, 0);
        #pragma unroll
        for (int r = 0; r < 32; ++r) {
            float v = bflo((uint)M2[r * 68 + lane]);
            int d = __builtin_amdgcn_readlane(dst, r);
            if (d != cur) {
                atomicAdd(&agg[(size_t)cur * H + lane], acc);
                acc = 0.f; cur = d;
            }
            acc += v;
        }
        atomicAdd(&agg[(size_t)cur * H + lane], acc);
    }
}

// ---------------- node/update kernel: block = 128 nodes ----------------
__global__ __launch_bounds__(256, 4) void node_mfma(
    const ushort* __restrict__ xbf, const float* __restrict__ agg,
    const float* __restrict__ node_attr, const ushort* __restrict__ wb,
    const float* __restrict__ b1, const float* __restrict__ b2,
    ushort* __restrict__ xnext, float* __restrict__ outf, int last) {
    __shared__ __align__(16) ushort lds[8704];   // WU1T [64][136]
    {
        const uint4* s4 = (const uint4*)wb;
        uint4* d4 = (uint4*)lds;
        for (int i = threadIdx.x; i < 1088; i += 256) d4[i] = s4[i];
    }
    __syncthreads();
    const ushort* W1T = lds;

    const int lane = threadIdx.x & 63;
    const int wv   = threadIdx.x >> 6;
    const int hi   = lane >> 5;
    const int l31  = lane & 31;
    const int n    = blockIdx.x * 128 + wv * 32 + l31;
    const int nc   = n < NN ? n : NN - 1;

    short8 aW2[4][2], aV1[2], aV2[2];
    #pragma unroll
    for (int m = 0; m < 2; ++m) {
        int r = l31 + 32 * m;
        aV1[m] = *(const short8*)(wb + 13312 + r * 16 + hi * 8);
        aV2[m] = *(const short8*)(wb + 14336 + r * 16 + hi * 8);
        #pragma unroll
        for (int s = 0; s < 4; ++s)
            aW2[s][m] = *(const short8*)(wb + 8704 + r * 72 + s * 16 + hi * 8);
    }

    float na[AD];
    #pragma unroll
    for (int a = 0; a < AD; ++a) na[a] = node_attr[(size_t)nc * AD + a];

    U8 bna;
    {
        uint g0 = pkbf(na[0], na[1]), g1 = pkbf(na[2], na[3]);
        uint g2 = pkbf(na[4], na[5]), g3 = pkbf(na[6], na[7]);
        uint g8 = pkbf(na[8], 0.f);
        bna.u[0] = hi ? g8 : g0;
        bna.u[1] = hi ? 0u : g1;
        bna.u[2] = hi ? 0u : g2;
        bna.u[3] = hi ? 0u : g3;
    }
    f32x16 gA0 = {}, gA1 = {};
    gA0 = MFMA(aV1[0], bna.v, gA0);
    gA1 = MFMA(aV1[1], bna.v, gA1);

    f32x16 mA0 = {}, mA1 = {};
    #pragma unroll
    for (int s = 0; s < 8; ++s) {
        short8 bx;
        if (s < 4) {
            bx = *(const short8*)(xbf + (size_t)nc * H + s * 16 + hi * 8);
        } else {
            const float* ap = agg + (size_t)nc * H + (s - 4) * 16 + hi * 8;
            float4 u0 = *(const float4*)ap;
            float4 u1 = *(const float4*)(ap + 4);
            U8 q;
            q.u[0] = pkbf(u0.x, u0.y); q.u[1] = pkbf(u0.z, u0.w);
            q.u[2] = pkbf(u1.x, u1.y); q.u[3] = pkbf(u1.z, u1.w);
            bx = q.v;
        }
        short8 a0 = *(const short8*)(W1T + l31 * 136 + s * 16 + hi * 8);
        short8 a1 = *(const short8*)(W1T + (l31 + 32) * 136 + s * 16 + hi * 8);
        mA0 = MFMA(a0, bx, mA0);
        mA1 = MFMA(a1, bx, mA1);
    }

    short8 bm[4];
    #pragma unroll
    for (int m = 0; m < 2; ++m) {
        const f32x16 mc = m ? mA1 : mA0;
        const f32x16 gc = m ? gA1 : gA0;
        float y[16];
        #pragma unroll
        for (int r = 0; r < 16; ++r) {
            int h0 = (r & 3) + 8 * (r >> 2) + 32 * m;
            float bb = hi ? b1[h0 + 4] : b1[h0];
            float v = fmaf(mc[r], gc[r], bb);
            y[r] = v / (1.f + __expf(-v));
        }
        #pragma unroll
        for (int g = 0; g < 2; ++g) {
            uint c0 = pkbf(y[g*8+0], y[g*8+1]);
            uint c1 = pkbf(y[g*8+2], y[g*8+3]);
            uint c2 = pkbf(y[g*8+4], y[g*8+5]);
            uint c3 = pkbf(y[g*8+6], y[g*8+7]);
            xhalf(c0, c2, hi);
            xhalf(c1, c3, hi);
            U8 q; q.u[0] = c0; q.u[1] = c1; q.u[2] = c2; q.u[3] = c3;
            bm[2*m + g] = q.v;
        }
    }

    f32x16 h0a = {}, h1a = {};
    h0a = MFMA(aV2[0], bna.v, h0a);
    h1a = MFMA(aV2[1], bna.v, h1a);
    f32x16 p0 = {}, p1 = {};
    #pragma unroll
    for (int s = 0; s < 4; ++s) {
        p0 = MFMA(aW2[s][0], bm[s], p0);
        p1 = MFMA(aW2[s][1], bm[s], p1);
    }

    #pragma unroll
    for (int m = 0; m < 2; ++m) {
        const f32x16 mc = m ? p1 : p0;
        const f32x16 gc = m ? h1a : h0a;
        float y[16];
        #pragma unroll
        for (int r = 0; r < 16; ++r) {
            int h0 = (r & 3) + 8 * (r >> 2) + 32 * m;
            float bb = hi ? b2[h0 + 4] : b2[h0];
            y[r] = fmaf(mc[r], gc[r], bb);
        }
        #pragma unroll
        for (int g = 0; g < 2; ++g) {
            uint c0 = pkbf(y[g*8+0], y[g*8+1]);
            uint c1 = pkbf(y[g*8+2], y[g*8+3]);
            uint c2 = pkbf(y[g*8+4], y[g*8+5]);
            uint c3 = pkbf(y[g*8+6], y[g*8+7]);
            xhalf(c0, c2, hi);
            xhalf(c1, c3, hi);
            int goff = (2*m + g) * 16 + hi * 8;
            U8 xb; xb.v = *(const short8*)(xbf + (size_t)nc * H + goff);
            float o[8];
            uint cc[4] = {c0, c1, c2, c3};
            #pragma unroll
            for (int j = 0; j < 4; ++j) {
                o[2*j]   = 0.7f * bflo((uint)xb.u[j]) + 0.3f * bflo(cc[j]);
                o[2*j+1] = 0.7f * bfhi((uint)xb.u[j]) + 0.3f * bfhi(cc[j]);
            }
            if (n < NN) {
                if (last) {
                    float4 w0 = {o[0], o[1], o[2], o[3]};
                    float4 w1 = {o[4], o[5], o[6], o[7]};
                    *(float4*)(outf + (size_t)n * H + goff)     = w0;
                    *(float4*)(outf + (size_t)n * H + goff + 4) = w1;
                } else {
                    U8 q;
                    #pragma unroll
                    for (int j = 0; j < 4; ++j) q.u[j] = pkbf(o[2*j], o[2*j+1]);
                    *(short8*)(xnext + (size_t)n * H + goff) = q.v;
                }
            }
        }
    }
}

extern "C" void kernel_launch(void* const* d_in, const int* in_sizes, int n_in,
                              void* d_out, int out_size, void* d_ws, size_t ws_size,
                              hipStream_t stream) {
    const float* x         = (const float*)d_in[0];
    const float* edge_attr = (const float*)d_in[1];
    const float* node_attr = (const float*)d_in[2];
    const float* amf       = (const float*)d_in[3];
    const float* Wm1 = (const float*)d_in[4];
    const float* Vm1 = (const float*)d_in[5];
    const float* bm1 = (const float*)d_in[6];
    const float* Wm2 = (const float*)d_in[7];
    const float* Vm2 = (const float*)d_in[8];
    const float* bm2 = (const float*)d_in[9];
    const float* Wu1 = (const float*)d_in[10];
    const float* Vu1 = (const float*)d_in[11];
    const float* bu1 = (const float*)d_in[12];
    const float* Wu2 = (const float*)d_in[13];
    const float* Vu2 = (const float*)d_in[14];
    const float* bu2 = (const float*)d_in[15];
    const int*   ei  = (const int*)d_in[16];

    float* out = (float*)d_out;
    float* agg = (float*)d_out;     // agg shares d_out (per-block row ownership in node_mfma)

    // ---- workspace layout ----
    ushort* xbf0 = (ushort*)d_ws;                    // NN*H
    ushort* xbf1 = xbf0 + (size_t)NN * H;            // NN*H
    ushort* wbE  = xbf1 + (size_t)NN * H;            // 2*17408
    ushort* wbN  = wbE + 2 * 17408;                  // 2*15360
    int* cnt     = (int*)(wbN + 2 * 15360);          // 51200
    int* btot    = cnt + 51200;                      // 256
    int* boff    = btot + 256;                       // 256
    int* partial = boff + 256;                       // 51200
    int* cursor  = partial + 51200;                  // 50000
    int* srcS    = cursor + 50000;                   // NE
    int* dstS    = srcS + NE;                        // NE
    float* amfS  = (float*)(dstS + NE);              // NE
    float* eaS   = amfS + NE;                        // NE*9

    prep_x<<<(NN * H / 8 + 255) / 256, 256, 0, stream>>>(x, xbf0);
    prep_w<<<256, 256, 0, stream>>>(Wm1, Vm1, Wm2, Vm2, Wu1, Vu1, Wu2, Vu2, wbE, wbN);

    // ---- CSR build (once per call) ----
    hipMemsetAsync(cnt, 0, 51200 * sizeof(int), stream);
    hist_k<<<(NE + 255) / 256, 256, 0, stream>>>(ei, cnt);
    scan1_k<<<200, 256, 0, stream>>>(cnt, partial, btot);
    scan2_k<<<1, 256, 0, stream>>>(btot, boff);
    scan3_k<<<200, 256, 0, stream>>>(partial, boff, cursor);
    fill_k<<<(NE + 255) / 256, 256, 0, stream>>>(ei, edge_attr, amf, cursor,
                                                 srcS, dstS, amfS, eaS);

    for (int l = 0; l < 2; ++l) {
        const ushort* xb = (l == 0) ? xbf0 : xbf1;
        hipMemsetAsync(agg, 0, (size_t)NN * H * sizeof(float), stream);
        edge_mfma<<<NE / 256, 256, 0, stream>>>(
            xb, eaS, amfS, srcS, dstS, wbE + (size_t)l * 17408,
            bm1 + l * H, bm2 + l * H, agg);
        node_mfma<<<(NN + 127) / 128, 256, 0, stream>>>(
            xb, agg, node_attr, wbN + (size_t)l * 15360,
            bu1 + l * H, bu2 + l * H, xbf1, out, (l == 1) ? 1 : 0);
    }
}

// Round 4
// 312.521 us; speedup vs baseline: 2.7333x; 1.2269x over previous
//
#include <hip/hip_runtime.h>
#include <hip/hip_bf16.h>

#define NN 50000
#define NE 800000
#define H  64
#define AD 9

typedef __attribute__((ext_vector_type(8)))  short short8;
typedef __attribute__((ext_vector_type(16))) float f32x16;
typedef unsigned int uint;
typedef unsigned short ushort;

union U8 { short8 v; uint u[4]; ushort s[8]; };

__device__ __forceinline__ f32x16 MFMA(short8 a, short8 b, f32x16 c) {
    return __builtin_amdgcn_mfma_f32_32x32x16_bf16(a, b, c, 0, 0, 0);
}

__device__ __forceinline__ ushort f2bf(float v) {
    __hip_bfloat16 b = __float2bfloat16(v);
    return *(ushort*)&b;
}
__device__ __forceinline__ uint pkbf(float a, float b) {
    uint r;
    asm volatile("v_cvt_pk_bf16_f32 %0, %1, %2" : "=v"(r) : "v"(a), "v"(b));
    return r;
}
__device__ __forceinline__ float bflo(uint u) { return __uint_as_float(u << 16); }
__device__ __forceinline__ float bfhi(uint u) { return __uint_as_float(u & 0xffff0000u); }

__device__ __forceinline__ float swish_fast(float v) {
    return v * __builtin_amdgcn_rcpf(1.f + __expf(-v));
}

// {a,b} -> a' = {a.lo_lanes, b.lo_lanes}, b' = {a.hi_lanes, b.hi_lanes}
__device__ __forceinline__ void xhalf(uint& a, uint& b) {
    asm("v_permlane32_swap_b32 %0, %1" : "+v"(a), "+v"(b));
}

// pack 16 accum values (one 32-row C-half) into 2 GEMM-B bf16 frags
__device__ __forceinline__ void pack16(const float* y, short8* out) {
    #pragma unroll
    for (int g = 0; g < 2; ++g) {
        uint c0 = pkbf(y[g*8+0], y[g*8+1]);
        uint c1 = pkbf(y[g*8+2], y[g*8+3]);
        uint c2 = pkbf(y[g*8+4], y[g*8+5]);
        uint c3 = pkbf(y[g*8+6], y[g*8+7]);
        xhalf(c0, c2);
        xhalf(c1, c3);
        U8 q; q.u[0] = c0; q.u[1] = c1; q.u[2] = c2; q.u[3] = c3;
        out[g] = q.v;
    }
}

// ---------------- prep: x -> bf16 ----------------
__global__ void prep_x(const float* __restrict__ x, ushort* __restrict__ xb) {
    int t = blockIdx.x * 256 + threadIdx.x;
    if (t >= NN * H / 8) return;
    const float* p = x + (size_t)t * 8;
    U8 o;
    #pragma unroll
    for (int j = 0; j < 8; ++j) o.s[j] = f2bf(p[j]);
    *(short8*)(xb + (size_t)t * 8) = o.v;
}

// ---------------- prep: weights -> transposed, padded, bf16 ----------------
__global__ void prep_w(const float* __restrict__ Wm1, const float* __restrict__ Vm1,
                       const float* __restrict__ Wm2, const float* __restrict__ Vm2,
                       const float* __restrict__ Wu1, const float* __restrict__ Vu1,
                       const float* __restrict__ Wu2, const float* __restrict__ Vu2,
                       ushort* __restrict__ wbE, ushort* __restrict__ wbN) {
    int t = blockIdx.x * 256 + threadIdx.x;
    float v = 0.f;
    if (t < 2 * 17408) {
        int l = t / 17408, o = t % 17408;
        if (o < 10752)      { int h = o / 168, k = o % 168;            if (k < 129) v = Wm1[l*8256 + k*64 + h]; }
        else if (o < 15360) { int o2 = o-10752; int h = o2/72, k = o2%72; if (k < 64)  v = Wm2[l*4096 + k*64 + h]; }
        else if (o < 16384) { int o2 = o-15360; int h = o2/16, a = o2%16; if (a < 9)   v = Vm1[l*576 + a*64 + h]; }
        else                { int o2 = o-16384; int h = o2/16, a = o2%16; if (a < 9)   v = Vm2[l*576 + a*64 + h]; }
        wbE[t] = f2bf(v);
    } else if (t < 2 * 17408 + 2 * 15360) {
        int u = t - 2 * 17408;
        int l = u / 15360, o = u % 15360;
        if (o < 8704)       { int h = o / 136, k = o % 136;            if (k < 128) v = Wu1[l*8192 + k*64 + h]; }
        else if (o < 13312) { int o2 = o-8704;  int h = o2/72, k = o2%72; if (k < 64)  v = Wu2[l*4096 + k*64 + h]; }
        else if (o < 14336) { int o2 = o-13312; int h = o2/16, a = o2%16; if (a < 9)   v = Vu1[l*576 + a*64 + h]; }
        else                { int o2 = o-14336; int h = o2/16, a = o2%16; if (a < 9)   v = Vu2[l*576 + a*64 + h]; }
        wbN[u] = f2bf(v);
    }
}

// ---------------- CSR build ----------------
__global__ void hist_k(const int* __restrict__ ei, int* __restrict__ cnt) {
    int t = blockIdx.x * 256 + threadIdx.x;
    if (t < NE) atomicAdd(&cnt[ei[NE + t]], 1);
}

__global__ void scan1_k(const int* __restrict__ cnt, int* __restrict__ partial,
                        int* __restrict__ btot) {
    __shared__ int sh[256];
    const int b = blockIdx.x, tid = threadIdx.x, i = b * 256 + tid;
    int c = cnt[i];
    sh[tid] = c; __syncthreads();
    int run = c;
    for (int off = 1; off < 256; off <<= 1) {
        int t = (tid >= off) ? sh[tid - off] : 0;
        __syncthreads();
        run += t; sh[tid] = run; __syncthreads();
    }
    partial[i] = run - c;
    if (tid == 255) btot[b] = run;
}

__global__ void scan2_k(const int* __restrict__ btot, int* __restrict__ boff) {
    __shared__ int sh[256];
    const int tid = threadIdx.x;
    int c = (tid < 200) ? btot[tid] : 0;
    sh[tid] = c; __syncthreads();
    int run = c;
    for (int off = 1; off < 256; off <<= 1) {
        int t = (tid >= off) ? sh[tid - off] : 0;
        __syncthreads();
        run += t; sh[tid] = run; __syncthreads();
    }
    boff[tid] = run - c;
}

__global__ void scan3_k(const int* __restrict__ partial, const int* __restrict__ boff,
                        int* __restrict__ cursor) {
    int b = blockIdx.x, i = b * 256 + threadIdx.x;
    if (i < NN) cursor[i] = partial[i] + boff[b];
}

__global__ void fill_k(const int* __restrict__ ei, const float* __restrict__ edge_attr,
                       const float* __restrict__ amf, int* __restrict__ cursor,
                       int* __restrict__ srcS, int* __restrict__ dstS,
                       uint4* __restrict__ eaLo, uint2* __restrict__ eaHi) {
    int e = blockIdx.x * 256 + threadIdx.x;
    if (e >= NE) return;
    const int dst = ei[NE + e], src = ei[e];
    const int pos = atomicAdd(&cursor[dst], 1);
    srcS[pos] = src; dstS[pos] = dst;
    float ea[AD];
    #pragma unroll
    for (int a = 0; a < AD; ++a) ea[a] = edge_attr[(size_t)e * AD + a];
    uint4 lo;
    lo.x = pkbf(ea[0], ea[1]); lo.y = pkbf(ea[2], ea[3]);
    lo.z = pkbf(ea[4], ea[5]); lo.w = pkbf(ea[6], ea[7]);
    eaLo[pos] = lo;
    uint2 hw;
    hw.x = pkbf(ea[8], 0.f); hw.y = pkbf(amf[e], 0.f);
    eaHi[pos] = hw;
}

// ---------------- edge message compute for one 32-edge group ----------------
struct M2Pack { short8 v[4]; };

__device__ __forceinline__ M2Pack msg_compute(
    const short8 bx[8], uint4 elo, uint2 ehi,
    const ushort* __restrict__ W1T, const ushort* __restrict__ wb,
    const short8 aW2[4][2], const short8 aV1[2], const short8 aV2[2],
    const float* __restrict__ b1, const float* __restrict__ b2,
    int l31, int hi) {
    U8 bea;
    bea.u[0] = hi ? ehi.x : elo.x;
    bea.u[1] = hi ? 0u : elo.y;
    bea.u[2] = hi ? 0u : elo.z;
    bea.u[3] = hi ? 0u : elo.w;

    f32x16 gA0 = {}, gA1 = {};
    gA0 = MFMA(aV1[0], bea.v, gA0);
    gA1 = MFMA(aV1[1], bea.v, gA1);

    // GEMM1: m1T[h][e] = sum_k W1[k][h] * [x_i | x_j | amf][e][k]
    f32x16 mA0 = {}, mA1 = {};
    #pragma unroll
    for (int s = 0; s < 8; ++s) {
        short8 a0 = *(const short8*)(W1T + l31 * 168 + s * 16 + hi * 8);
        short8 a1 = *(const short8*)(W1T + (l31 + 32) * 168 + s * 16 + hi * 8);
        mA0 = MFMA(a0, bx[s], mA0);
        mA1 = MFMA(a1, bx[s], mA1);
    }
    {
        U8 ba;
        ba.u[0] = hi ? 0u : ehi.y;
        ba.u[1] = 0; ba.u[2] = 0; ba.u[3] = 0;
        short8 a0 = *(const short8*)(W1T + l31 * 168 + 128 + hi * 8);
        short8 a1 = *(const short8*)(W1T + (l31 + 32) * 168 + 128 + hi * 8);
        mA0 = MFMA(a0, ba.v, mA0);
        mA1 = MFMA(a1, ba.v, mA1);
    }

    // swish(m*gate + b1) -> GEMM2 B-frags
    short8 bm[4];
    #pragma unroll
    for (int m = 0; m < 2; ++m) {
        const f32x16 mc = m ? mA1 : mA0;
        const f32x16 gc = m ? gA1 : gA0;
        float y[16];
        #pragma unroll
        for (int r = 0; r < 16; ++r) {
            int h0 = (r & 3) + 8 * (r >> 2) + 32 * m;
            float bb = hi ? b1[h0 + 4] : b1[h0];
            y[r] = swish_fast(fmaf(mc[r], gc[r], bb));
        }
        pack16(y, &bm[2 * m]);
    }

    // GEMM2 + gate2
    f32x16 h0a = {}, h1a = {};
    h0a = MFMA(aV2[0], bea.v, h0a);
    h1a = MFMA(aV2[1], bea.v, h1a);
    f32x16 p0 = {}, p1 = {};
    #pragma unroll
    for (int s = 0; s < 4; ++s) {
        p0 = MFMA(aW2[s][0], bm[s], p0);
        p1 = MFMA(aW2[s][1], bm[s], p1);
    }

    M2Pack out;
    #pragma unroll
    for (int m = 0; m < 2; ++m) {
        const f32x16 mc = m ? p1 : p0;
        const f32x16 gc = m ? h1a : h0a;
        float y[16];
        #pragma unroll
        for (int r = 0; r < 16; ++r) {
            int h0 = (r & 3) + 8 * (r >> 2) + 32 * m;
            float bb = hi ? b2[h0 + 4] : b2[h0];
            y[r] = swish_fast(fmaf(mc[r], gc[r], bb));
        }
        pack16(y, &out.v[2 * m]);
    }
    return out;
}

__device__ __forceinline__ void gather_x(short8 bx[8], const ushort* __restrict__ xbf,
                                         int dst, int src, int hi) {
    const ushort* xd = xbf + (size_t)dst * H;
    const ushort* xs = xbf + (size_t)src * H;
    #pragma unroll
    for (int s = 0; s < 8; ++s)
        bx[s] = *(const short8*)((s < 4 ? xd : xs) + (s & 3) * 16 + hi * 8);
}

__device__ __forceinline__ void seg_reduce(const ushort* __restrict__ M2, int dst,
                                           float* __restrict__ agg, int lane) {
    float acc = 0.f;
    int cur = __builtin_amdgcn_readlane(dst, 0);
    #pragma unroll
    for (int r = 0; r < 32; ++r) {
        float v = bflo((uint)M2[r * 68 + lane]);
        int d = __builtin_amdgcn_readlane(dst, r);
        if (d != cur) {
            atomicAdd(&agg[(size_t)cur * H + lane], acc);
            acc = 0.f; cur = d;
        }
        acc += v;
    }
    atomicAdd(&agg[(size_t)cur * H + lane], acc);
}

// ---------------- edge/message kernel: block = 256 dst-sorted edges ----------------
__global__ __launch_bounds__(256, 4) void edge_mfma(
    const ushort* __restrict__ xbf, const uint4* __restrict__ eaLo,
    const uint2* __restrict__ eaHi, const int* __restrict__ srcS,
    const int* __restrict__ dstS, const ushort* __restrict__ wb,
    const float* __restrict__ b1, const float* __restrict__ b2,
    float* __restrict__ agg) {
    // LDS: W1T [64][168] (10752 ushorts) | per-wave M2 [32][68] bf16
    __shared__ __align__(16) ushort lds[10752 + 4 * 32 * 68];
    {
        const uint4* s4 = (const uint4*)wb;
        uint4* d4 = (uint4*)lds;
        for (int i = threadIdx.x; i < 1344; i += 256) d4[i] = s4[i];
    }
    __syncthreads();
    const ushort* W1T = lds;

    const int lane = threadIdx.x & 63;
    const int wv   = threadIdx.x >> 6;
    const int hi   = lane >> 5;
    const int l31  = lane & 31;
    ushort* M2 = lds + 10752 + wv * (32 * 68);

    const int i0 = blockIdx.x * 256 + wv * 64 + l31;
    const int i1 = i0 + 32;

    // stage both groups' indices + packed attrs
    const int dst0 = dstS[i0], src0 = srcS[i0];
    const int dst1 = dstS[i1], src1 = srcS[i1];
    const uint4 elo0 = eaLo[i0], elo1 = eaLo[i1];
    const uint2 ehi0 = eaHi[i0], ehi1 = eaHi[i1];

    // pinned A-frags from global (L2-hot): W2T, V1T, V2T
    short8 aW2[4][2], aV1[2], aV2[2];
    #pragma unroll
    for (int m = 0; m < 2; ++m) {
        int r = l31 + 32 * m;
        aV1[m] = *(const short8*)(wb + 15360 + r * 16 + hi * 8);
        aV2[m] = *(const short8*)(wb + 16384 + r * 16 + hi * 8);
        #pragma unroll
        for (int s = 0; s < 4; ++s)
            aW2[s][m] = *(const short8*)(wb + 10752 + r * 72 + s * 16 + hi * 8);
    }

    // ---- group 0 ----
    short8 bx0[8];
    gather_x(bx0, xbf, dst0, src0, hi);
    M2Pack p0 = msg_compute(bx0, elo0, ehi0, W1T, wb, aW2, aV1, aV2, b1, b2, l31, hi);

    // prefetch group 1's x rows before group 0's reduce
    short8 bx1[8];
    gather_x(bx1, xbf, dst1, src1, hi);

    #pragma unroll
    for (int j = 0; j < 4; ++j)
        *(short8*)(M2 + l31 * 68 + j * 16 + hi * 8) = p0.v[j];
    seg_reduce(M2, dst0, agg, lane);

    // ---- group 1 ----
    M2Pack p1 = msg_compute(bx1, elo1, ehi1, W1T, wb, aW2, aV1, aV2, b1, b2, l31, hi);
    #pragma unroll
    for (int j = 0; j < 4; ++j)
        *(short8*)(M2 + l31 * 68 + j * 16 + hi * 8) = p1.v[j];
    seg_reduce(M2, dst1, agg, lane);
}

// ---------------- node/update kernel: block = 128 nodes ----------------
__global__ __launch_bounds__(256, 4) void node_mfma(
    const ushort* __restrict__ xbf, const float* __restrict__ agg,
    const float* __restrict__ node_attr, const ushort* __restrict__ wb,
    const float* __restrict__ b1, const float* __restrict__ b2,
    ushort* __restrict__ xnext, float* __restrict__ outf, int last) {
    __shared__ __align__(16) ushort lds[8704];   // WU1T [64][136]
    {
        const uint4* s4 = (const uint4*)wb;
        uint4* d4 = (uint4*)lds;
        for (int i = threadIdx.x; i < 1088; i += 256) d4[i] = s4[i];
    }
    __syncthreads();
    const ushort* W1T = lds;

    const int lane = threadIdx.x & 63;
    const int wv   = threadIdx.x >> 6;
    const int hi   = lane >> 5;
    const int l31  = lane & 31;
    const int n    = blockIdx.x * 128 + wv * 32 + l31;
    const int nc   = n < NN ? n : NN - 1;

    short8 aW2[4][2], aV1[2], aV2[2];
    #pragma unroll
    for (int m = 0; m < 2; ++m) {
        int r = l31 + 32 * m;
        aV1[m] = *(const short8*)(wb + 13312 + r * 16 + hi * 8);
        aV2[m] = *(const short8*)(wb + 14336 + r * 16 + hi * 8);
        #pragma unroll
        for (int s = 0; s < 4; ++s)
            aW2[s][m] = *(const short8*)(wb + 8704 + r * 72 + s * 16 + hi * 8);
    }

    float na[AD];
    #pragma unroll
    for (int a = 0; a < AD; ++a) na[a] = node_attr[(size_t)nc * AD + a];

    U8 bna;
    {
        uint g0 = pkbf(na[0], na[1]), g1 = pkbf(na[2], na[3]);
        uint g2 = pkbf(na[4], na[5]), g3 = pkbf(na[6], na[7]);
        uint g8 = pkbf(na[8], 0.f);
        bna.u[0] = hi ? g8 : g0;
        bna.u[1] = hi ? 0u : g1;
        bna.u[2] = hi ? 0u : g2;
        bna.u[3] = hi ? 0u : g3;
    }
    f32x16 gA0 = {}, gA1 = {};
    gA0 = MFMA(aV1[0], bna.v, gA0);
    gA1 = MFMA(aV1[1], bna.v, gA1);

    f32x16 mA0 = {}, mA1 = {};
    #pragma unroll
    for (int s = 0; s < 8; ++s) {
        short8 bx;
        if (s < 4) {
            bx = *(const short8*)(xbf + (size_t)nc * H + s * 16 + hi * 8);
        } else {
            const float* ap = agg + (size_t)nc * H + (s - 4) * 16 + hi * 8;
            float4 u0 = *(const float4*)ap;
            float4 u1 = *(const float4*)(ap + 4);
            U8 q;
            q.u[0] = pkbf(u0.x, u0.y); q.u[1] = pkbf(u0.z, u0.w);
            q.u[2] = pkbf(u1.x, u1.y); q.u[3] = pkbf(u1.z, u1.w);
            bx = q.v;
        }
        short8 a0 = *(const short8*)(W1T + l31 * 136 + s * 16 + hi * 8);
        short8 a1 = *(const short8*)(W1T + (l31 + 32) * 136 + s * 16 + hi * 8);
        mA0 = MFMA(a0, bx, mA0);
        mA1 = MFMA(a1, bx, mA1);
    }

    short8 bm[4];
    #pragma unroll
    for (int m = 0; m < 2; ++m) {
        const f32x16 mc = m ? mA1 : mA0;
        const f32x16 gc = m ? gA1 : gA0;
        float y[16];
        #pragma unroll
        for (int r = 0; r < 16; ++r) {
            int h0 = (r & 3) + 8 * (r >> 2) + 32 * m;
            float bb = hi ? b1[h0 + 4] : b1[h0];
            y[r] = swish_fast(fmaf(mc[r], gc[r], bb));
        }
        pack16(y, &bm[2 * m]);
    }

    f32x16 h0a = {}, h1a = {};
    h0a = MFMA(aV2[0], bna.v, h0a);
    h1a = MFMA(aV2[1], bna.v, h1a);
    f32x16 p0 = {}, p1 = {};
    #pragma unroll
    for (int s = 0; s < 4; ++s) {
        p0 = MFMA(aW2[s][0], bm[s], p0);
        p1 = MFMA(aW2[s][1], bm[s], p1);
    }

    #pragma unroll
    for (int m = 0; m < 2; ++m) {
        const f32x16 mc = m ? p1 : p0;
        const f32x16 gc = m ? h1a : h0a;
        float y[16];
        #pragma unroll
        for (int r = 0; r < 16; ++r) {
            int h0 = (r & 3) + 8 * (r >> 2) + 32 * m;
            float bb = hi ? b2[h0 + 4] : b2[h0];
            y[r] = fmaf(mc[r], gc[r], bb);
        }
        #pragma unroll
        for (int g = 0; g < 2; ++g) {
            uint c0 = pkbf(y[g*8+0], y[g*8+1]);
            uint c1 = pkbf(y[g*8+2], y[g*8+3]);
            uint c2 = pkbf(y[g*8+4], y[g*8+5]);
            uint c3 = pkbf(y[g*8+6], y[g*8+7]);
            xhalf(c0, c2);
            xhalf(c1, c3);
            int goff = (2*m + g) * 16 + hi * 8;
            U8 xb; xb.v = *(const short8*)(xbf + (size_t)nc * H + goff);
            float o[8];
            uint cc[4] = {c0, c1, c2, c3};
            #pragma unroll
            for (int j = 0; j < 4; ++j) {
                o[2*j]   = 0.7f * bflo((uint)xb.u[j]) + 0.3f * bflo(cc[j]);
                o[2*j+1] = 0.7f * bfhi((uint)xb.u[j]) + 0.3f * bfhi(cc[j]);
            }
            if (n < NN) {
                if (last) {
                    float4 w0 = {o[0], o[1], o[2], o[3]};
                    float4 w1 = {o[4], o[5], o[6], o[7]};
                    *(float4*)(outf + (size_t)n * H + goff)     = w0;
                    *(float4*)(outf + (size_t)n * H + goff + 4) = w1;
                } else {
                    U8 q;
                    #pragma unroll
                    for (int j = 0; j < 4; ++j) q.u[j] = pkbf(o[2*j], o[2*j+1]);
                    *(short8*)(xnext + (size_t)n * H + goff) = q.v;
                }
            }
        }
    }
}

extern "C" void kernel_launch(void* const* d_in, const int* in_sizes, int n_in,
                              void* d_out, int out_size, void* d_ws, size_t ws_size,
                              hipStream_t stream) {
    const float* x         = (const float*)d_in[0];
    const float* edge_attr = (const float*)d_in[1];
    const float* node_attr = (const float*)d_in[2];
    const float* amf       = (const float*)d_in[3];
    const float* Wm1 = (const float*)d_in[4];
    const float* Vm1 = (const float*)d_in[5];
    const float* bm1 = (const float*)d_in[6];
    const float* Wm2 = (const float*)d_in[7];
    const float* Vm2 = (const float*)d_in[8];
    const float* bm2 = (const float*)d_in[9];
    const float* Wu1 = (const float*)d_in[10];
    const float* Vu1 = (const float*)d_in[11];
    const float* bu1 = (const float*)d_in[12];
    const float* Wu2 = (const float*)d_in[13];
    const float* Vu2 = (const float*)d_in[14];
    const float* bu2 = (const float*)d_in[15];
    const int*   ei  = (const int*)d_in[16];

    float* out = (float*)d_out;
    float* agg = (float*)d_out;     // agg shares d_out (per-block row ownership in node_mfma)

    // ---- workspace layout (16B-aligned blocks) ----
    ushort* xbf0 = (ushort*)d_ws;                    // NN*H
    ushort* xbf1 = xbf0 + (size_t)NN * H;            // NN*H
    ushort* wbE  = xbf1 + (size_t)NN * H;            // 2*17408
    ushort* wbN  = wbE + 2 * 17408;                  // 2*15360
    int* cnt     = (int*)(wbN + 2 * 15360);          // 51200
    int* btot    = cnt + 51200;                      // 256
    int* boff    = btot + 256;                       // 256
    int* partial = boff + 256;                       // 51200
    int* cursor  = partial + 51200;                  // 50000 (+pad 48 to keep 16B align)
    int* srcS    = cursor + 50048;                   // NE
    int* dstS    = srcS + NE;                        // NE
    uint4* eaLo  = (uint4*)(dstS + NE);              // NE * 16B
    uint2* eaHi  = (uint2*)(eaLo + NE);              // NE * 8B

    prep_x<<<(NN * H / 8 + 255) / 256, 256, 0, stream>>>(x, xbf0);
    prep_w<<<256, 256, 0, stream>>>(Wm1, Vm1, Wm2, Vm2, Wu1, Vu1, Wu2, Vu2, wbE, wbN);

    // ---- CSR build (once per call) ----
    hipMemsetAsync(cnt, 0, 51200 * sizeof(int), stream);
    hist_k<<<(NE + 255) / 256, 256, 0, stream>>>(ei, cnt);
    scan1_k<<<200, 256, 0, stream>>>(cnt, partial, btot);
    scan2_k<<<1, 256, 0, stream>>>(btot, boff);
    scan3_k<<<200, 256, 0, stream>>>(partial, boff, cursor);
    fill_k<<<(NE + 255) / 256, 256, 0, stream>>>(ei, edge_attr, amf, cursor,
                                                 srcS, dstS, eaLo, eaHi);

    for (int l = 0; l < 2; ++l) {
        const ushort* xb = (l == 0) ? xbf0 : xbf1;
        hipMemsetAsync(agg, 0, (size_t)NN * H * sizeof(float), stream);
        edge_mfma<<<NE / 256, 256, 0, stream>>>(
            xb, eaLo, eaHi, srcS, dstS, wbE + (size_t)l * 17408,
            bm1 + l * H, bm2 + l * H, agg);
        node_mfma<<<(NN + 127) / 128, 256, 0, stream>>>(
            xb, agg, node_attr, wbN + (size_t)l * 15360,
            bu1 + l * H, bu2 + l * H, xbf1, out, (l == 1) ? 1 : 0);
    }
}